// Round 7
// baseline (373.799 us; speedup 1.0000x reference)
//
#include <hip/hip_runtime.h>
#include <hip/hip_bf16.h>

#define D 128            // D_IN == D_OUT == 128
#define D4 32            // D/4 float4s per row
#define CHUNK 3072       // edges per histb / bscatter block (1024 threads)
#define MAXB 2048        // max buckets => n_nodes <= 131072 for fast path

typedef __attribute__((ext_vector_type(8))) short bf16x8;
typedef __attribute__((ext_vector_type(4))) float f32x4;

// float -> bf16 round-to-nearest-even
static __device__ __forceinline__ unsigned short f2bf(float f) {
    unsigned u = __float_as_uint(f);
    u += 0x7FFFu + ((u >> 16) & 1u);
    return (unsigned short)(u >> 16);
}
static __device__ __forceinline__ float bf2f(unsigned short u) {
    return __uint_as_float(((unsigned)u) << 16);
}

// ---------------------------------------------------------------------------
// GEMM via bf16 MFMA: hwb[n,:] = bf16( (h[n,:] @ W) * norm[n] )
// ---------------------------------------------------------------------------
__global__ __launch_bounds__(256) void gemm_mfma_kernel(
    const float* __restrict__ h, const float* __restrict__ W,
    const float* __restrict__ norm, unsigned short* __restrict__ hwb,
    int n_nodes)
{
    __shared__ unsigned short As[64 * 136];    // [row][k] bf16, padded stride
    __shared__ unsigned short Bs[128 * 136];   // [col][k] bf16 (W^T), padded

    const int t = threadIdx.x;
    const int row0 = blockIdx.x * 64;

    #pragma unroll
    for (int i = 0; i < 16; ++i) {
        const int idx = t + 256 * i;           // float4 index over 128x32
        const int k = idx >> 5;
        const int c = (idx & 31) * 4;
        const float4 w = ((const float4*)W)[idx];
        Bs[(c + 0) * 136 + k] = f2bf(w.x);
        Bs[(c + 1) * 136 + k] = f2bf(w.y);
        Bs[(c + 2) * 136 + k] = f2bf(w.z);
        Bs[(c + 3) * 136 + k] = f2bf(w.w);
    }
    #pragma unroll
    for (int i = 0; i < 8; ++i) {
        const int idx = t + 256 * i;           // float4 index over 64x32
        const int r = idx >> 5;
        const int kq = idx & 31;
        long gr = row0 + r; if (gr >= n_nodes) gr = n_nodes - 1;
        const float4 a = ((const float4*)(h + gr * D))[kq];
        ushort4 o;
        o.x = f2bf(a.x); o.y = f2bf(a.y); o.z = f2bf(a.z); o.w = f2bf(a.w);
        *(ushort4*)&As[r * 136 + kq * 4] = o;
    }
    __syncthreads();

    const int wv = t >> 6;
    const int lane = t & 63;
    const int m = lane & 15;
    const int quad = lane >> 4;

    f32x4 acc[8];
    #pragma unroll
    for (int nt = 0; nt < 8; ++nt) { f32x4 z = {0.f, 0.f, 0.f, 0.f}; acc[nt] = z; }

    #pragma unroll
    for (int kt = 0; kt < 4; ++kt) {
        const bf16x8 af = *(const bf16x8*)&As[(wv * 16 + m) * 136 + kt * 32 + quad * 8];
        #pragma unroll
        for (int nt = 0; nt < 8; ++nt) {
            const bf16x8 bfr = *(const bf16x8*)&Bs[(nt * 16 + m) * 136 + kt * 32 + quad * 8];
            acc[nt] = __builtin_amdgcn_mfma_f32_16x16x32_bf16(af, bfr, acc[nt], 0, 0, 0);
        }
    }

    float nv[4];
    #pragma unroll
    for (int i = 0; i < 4; ++i) {
        const int gr = row0 + wv * 16 + quad * 4 + i;
        nv[i] = (gr < n_nodes) ? norm[gr] : 0.f;
    }
    #pragma unroll
    for (int nt = 0; nt < 8; ++nt) {
        #pragma unroll
        for (int i = 0; i < 4; ++i) {
            const int gr = row0 + wv * 16 + quad * 4 + i;
            if (gr < n_nodes)
                hwb[(size_t)gr * D + nt * 16 + m] = f2bf(acc[nt][i] * nv[i]);
        }
    }
}

// ---------------------------------------------------------------------------
// histb: per-chunk LDS bucket histogram -> H[g][*]. NO global atomics.
// Block 0 zeroes the dummy hwb row.
// ---------------------------------------------------------------------------
__global__ __launch_bounds__(1024) void histb_kernel(
    const int* __restrict__ dst, int* __restrict__ H,
    unsigned short* __restrict__ hwb, int n_edges, int n_nodes)
{
    __shared__ int lbh[MAXB];
    const int t = threadIdx.x;
    const int g = blockIdx.x;
    for (int i = t; i < MAXB; i += 1024) lbh[i] = 0;
    if (g == 0 && t < 32) {
        ushort4 z; z.x = z.y = z.z = z.w = 0;
        ((ushort4*)(hwb + (size_t)n_nodes * D))[t] = z;
    }
    __syncthreads();
    const int e0 = g * CHUNK;
    const int e1 = min(e0 + CHUNK, n_edges);
    for (int e = e0 + t; e < e1; e += 1024)
        atomicAdd(&lbh[dst[e] >> 6], 1);
    __syncthreads();
    for (int i = t; i < MAXB; i += 1024)
        H[(size_t)g * MAXB + i] = lbh[i];
}

// ---------------------------------------------------------------------------
// colscan: column-wise exclusive scan of H over chunks; H[g][b] becomes the
// within-bucket start offset of chunk g; bcnt[b] = bucket total. Coalesced.
// ---------------------------------------------------------------------------
__global__ __launch_bounds__(256) void colscan_kernel(
    int* __restrict__ H, int* __restrict__ bcnt, int nchunks)
{
    const int b = blockIdx.x * 256 + threadIdx.x;   // grid = MAXB/256 blocks
    int run = 0;
    for (int g = 0; g < nchunks; ++g) {
        const size_t idx = (size_t)g * MAXB + b;
        const int v = H[idx];
        H[idx] = run;
        run += v;
    }
    bcnt[b] = run;
}

// ---------------------------------------------------------------------------
// bscan: single block, exclusive scan of MAXB bucket counts -> boff.
// ---------------------------------------------------------------------------
__global__ __launch_bounds__(256) void bscan_kernel(
    const int* __restrict__ bcnt, int* __restrict__ boff)
{
    __shared__ int tmp[256];
    const int t = threadIdx.x;
    int v[8];
    int s = 0;
    #pragma unroll
    for (int k = 0; k < 8; ++k) { v[k] = bcnt[t * 8 + k]; s += v[k]; }
    tmp[t] = s;
    __syncthreads();
    for (int ofs = 1; ofs < 256; ofs <<= 1) {
        int x = (t >= ofs) ? tmp[t - ofs] : 0;
        __syncthreads();
        tmp[t] += x;
        __syncthreads();
    }
    int run = tmp[t] - s;
    #pragma unroll
    for (int k = 0; k < 8; ++k) {
        boff[t * 8 + k] = run;
        run += v[k];
    }
    if (t == 255) boff[MAXB] = run;
}

// ---------------------------------------------------------------------------
// bscatter: lofs = boff[b] + H[g][b] (deterministic, no global atomics);
// LDS-ranked scatter of packed records (src | (dst&63)<<17) into ebuf.
// ---------------------------------------------------------------------------
__global__ __launch_bounds__(1024) void bscatter_kernel(
    const int* __restrict__ src, const int* __restrict__ dst,
    const int* __restrict__ H, const int* __restrict__ boff,
    unsigned int* __restrict__ ebuf, int n_edges)
{
    __shared__ int lbh[MAXB];
    __shared__ int lofs[MAXB];
    const int t = threadIdx.x;
    const int g = blockIdx.x;
    for (int i = t; i < MAXB; i += 1024) {
        lbh[i] = 0;
        lofs[i] = boff[i] + H[(size_t)g * MAXB + i];
    }
    __syncthreads();
    const int e0 = g * CHUNK;
    const int e1 = min(e0 + CHUNK, n_edges);
    for (int e = e0 + t; e < e1; e += 1024) {
        const int d = dst[e];
        const int bk = d >> 6;
        const int r = atomicAdd(&lbh[bk], 1);     // LDS only
        ebuf[lofs[bk] + r] = (unsigned)src[e] | ((unsigned)(d & 63) << 17);
    }
}

// ---------------------------------------------------------------------------
// bucket_count: per-node counts derived from each bucket's ebuf window via
// LDS counters. Replaces 1.6M global cnt atomics (and the cnt memset).
// ---------------------------------------------------------------------------
__global__ __launch_bounds__(256) void bucket_count_kernel(
    const unsigned int* __restrict__ ebuf, const int* __restrict__ boff,
    int* __restrict__ cnt, int n_nodes)
{
    __shared__ int lc[64];
    const int t = threadIdx.x;
    const int b = blockIdx.x;
    if (t < 64) lc[t] = 0;
    __syncthreads();
    const int e0 = boff[b], e1 = boff[b + 1];
    for (int e = e0 + t; e < e1; e += 256)
        atomicAdd(&lc[(ebuf[e] >> 17) & 63], 1);
    __syncthreads();
    if (t < 64) {
        const int gn = b * 64 + t;
        if (gn < n_nodes) cnt[gn] = lc[t];
    }
}

// ---------------------------------------------------------------------------
// Per-node padded scan: off = exclusive scan of cnt padded to x8.
// ---------------------------------------------------------------------------
__global__ __launch_bounds__(256) void scan_blocks_kernel(
    const int* __restrict__ cnt, int* __restrict__ off,
    int* __restrict__ bsums, int n)
{
    __shared__ int tmp[256];
    const int t = threadIdx.x;
    const int base = blockIdx.x * 1024 + t * 4;

    int v[4];
    int s = 0;
    #pragma unroll
    for (int k = 0; k < 4; ++k) {
        int c = (base + k < n) ? cnt[base + k] : 0;
        v[k] = (c + 7) & ~7;
        s += v[k];
    }
    tmp[t] = s;
    __syncthreads();
    for (int ofs = 1; ofs < 256; ofs <<= 1) {
        int x = (t >= ofs) ? tmp[t - ofs] : 0;
        __syncthreads();
        tmp[t] += x;
        __syncthreads();
    }
    int run = tmp[t] - s;
    #pragma unroll
    for (int k = 0; k < 4; ++k) {
        if (base + k < n) off[base + k] = run;
        run += v[k];
    }
    if (t == 255) bsums[blockIdx.x] = tmp[255];
}

__global__ __launch_bounds__(256) void scan_top_kernel(int* __restrict__ bsums, int nb)
{
    __shared__ int tmp[256];
    const int t = threadIdx.x;
    const int orig = (t < nb) ? bsums[t] : 0;
    tmp[t] = orig;
    __syncthreads();
    for (int ofs = 1; ofs < 256; ofs <<= 1) {
        int x = (t >= ofs) ? tmp[t - ofs] : 0;
        __syncthreads();
        tmp[t] += x;
        __syncthreads();
    }
    if (t < nb) bsums[t] = tmp[t] - orig;
}

__global__ __launch_bounds__(256) void scan_add_kernel(
    int* __restrict__ off, const int* __restrict__ bsums, int n)
{
    const int t = threadIdx.x;
    const int base = blockIdx.x * 1024 + t * 4;
    const int add = bsums[blockIdx.x];
    #pragma unroll
    for (int k = 0; k < 4; ++k) {
        const int i = base + k;
        if (i < n) off[i] += add;
    }
}

// ---------------------------------------------------------------------------
// fill_local: one block per bucket (64 nodes). LDS cursors; scatter srcs
// within the bucket's contiguous window, then write pad slots.
// ---------------------------------------------------------------------------
__global__ __launch_bounds__(256) void fill_local_kernel(
    const unsigned int* __restrict__ ebuf, const int* __restrict__ boff,
    const int* __restrict__ off, const int* __restrict__ cnt,
    int* __restrict__ srcs, int n_nodes)
{
    __shared__ int lcur[64];
    const int t = threadIdx.x;
    const int b = blockIdx.x;
    const int gn0 = b * 64;
    if (t < 64) {
        const int gn = gn0 + t;
        lcur[t] = (gn < n_nodes) ? off[gn] : 0;
    }
    __syncthreads();
    const int e0 = boff[b], e1 = boff[b + 1];
    for (int e = e0 + t; e < e1; e += 256) {
        const unsigned rec = ebuf[e];
        const int loc = (rec >> 17) & 63;
        const int pos = atomicAdd(&lcur[loc], 1);
        srcs[pos] = (int)(rec & 0x1FFFFu);
    }
    for (int w = t; w < 512; w += 256) {
        const int ln = w >> 3, k = w & 7;
        const int gn = gn0 + ln;
        if (gn < n_nodes) {
            const int c = cnt[gn];
            const int pad = (8 - (c & 7)) & 7;
            if (k < pad) srcs[off[gn] + c + k] = n_nodes;
        }
    }
}

// ---------------------------------------------------------------------------
// Aggregation: 8 nodes/block, 32 lanes/node, ushort4 bf16 gathers, MLP=8.
// Fuses out = agg*norm + bias.
// ---------------------------------------------------------------------------
__global__ __launch_bounds__(256) void agg_kernel(
    const unsigned short* __restrict__ hwb, const int* __restrict__ srcs,
    const int* __restrict__ off, const int* __restrict__ cnt,
    const float* __restrict__ norm, const float* __restrict__ bias,
    float* __restrict__ out, int n_nodes)
{
    const int t = threadIdx.x;
    const int sub = t >> 5;
    const int lane32 = t & 31;
    const int node = blockIdx.x * 8 + sub;
    if (node >= n_nodes) return;

    const int start = off[node];
    const int deg = cnt[node];
    const int nb8 = (deg + 7) >> 3;

    const ushort4* hw4 = (const ushort4*)hwb;

    float4 acc; acc.x = acc.y = acc.z = acc.w = 0.0f;
    int myidx = 0;

    for (int b = 0; b < nb8; ++b) {
        const int q = b & 3;
        if (q == 0) myidx = srcs[start + b * 8 + lane32];
        ushort4 v[8];
        #pragma unroll
        for (int jj = 0; jj < 8; ++jj) {
            const int s = __shfl(myidx, q * 8 + jj, 32);
            v[jj] = hw4[(long)s * D4 + lane32];
        }
        #pragma unroll
        for (int jj = 0; jj < 8; ++jj) {
            acc.x += bf2f(v[jj].x);
            acc.y += bf2f(v[jj].y);
            acc.z += bf2f(v[jj].z);
            acc.w += bf2f(v[jj].w);
        }
    }

    const float nv = norm[node];
    const float4 bs = ((const float4*)bias)[lane32];
    float4 o;
    o.x = acc.x * nv + bs.x;
    o.y = acc.y * nv + bs.y;
    o.z = acc.z * nv + bs.z;
    o.w = acc.w * nv + bs.w;
    ((float4*)out)[(long)node * D4 + lane32] = o;
}

// ---------------------------------------------------------------------------
// Fallback path: atomic scatter from bf16 hwb + finalize (ws too small).
// ---------------------------------------------------------------------------
__global__ __launch_bounds__(256) void scatter_kernel(
    const unsigned short* __restrict__ hwb, const int* __restrict__ src,
    const int* __restrict__ dst, float* __restrict__ out, int n_edges)
{
    const int idx = blockIdx.x * 256 + threadIdx.x;
    if (idx >= n_edges * D4) return;
    const int e = idx >> 5;
    const int g = idx & 31;
    const int s = src[e];
    const int d = dst[e];
    const ushort4 v = ((const ushort4*)hwb)[(long)s * D4 + g];
    float* o = out + (long)d * D + g * 4;
    atomicAdd(o + 0, bf2f(v.x));
    atomicAdd(o + 1, bf2f(v.y));
    atomicAdd(o + 2, bf2f(v.z));
    atomicAdd(o + 3, bf2f(v.w));
}

__global__ __launch_bounds__(256) void finalize_kernel(
    float* __restrict__ out, const float* __restrict__ norm,
    const float* __restrict__ bias, int n_nodes)
{
    const int idx = blockIdx.x * 256 + threadIdx.x;
    if (idx >= n_nodes * D4) return;
    const int n = idx >> 5;
    const int g = idx & 31;
    float4 v = ((float4*)out)[idx];
    const float nv = norm[n];
    const float4 b = ((const float4*)bias)[g];
    v.x = v.x * nv + b.x;
    v.y = v.y * nv + b.y;
    v.z = v.z * nv + b.z;
    v.w = v.w * nv + b.w;
    ((float4*)out)[idx] = v;
}

extern "C" void kernel_launch(void* const* d_in, const int* in_sizes, int n_in,
                              void* d_out, int out_size, void* d_ws, size_t ws_size,
                              hipStream_t stream) {
    const float* h    = (const float*)d_in[0];
    const float* norm = (const float*)d_in[1];
    const int*   src  = (const int*)d_in[2];
    const int*   dst  = (const int*)d_in[3];
    const float* W    = (const float*)d_in[4];
    const float* bias = (const float*)d_in[5];
    float* out = (float*)d_out;

    const int n_nodes = in_sizes[1];
    const int n_edges = in_sizes[2];

    const int srcs_len = n_edges + 8 * n_nodes + 64;
    const int NB    = (n_nodes + 1023) / 1024;       // per-node scan blocks
    const int NBUCK = (n_nodes + 63) >> 6;           // buckets (64 nodes each)
    const int EB    = (n_edges + CHUNK - 1) / CHUNK; // edge chunks (521)

    // ---- workspace layout (256B aligned) ----
    size_t p = 0;
    auto take = [&](size_t bytes) {
        size_t cur = p;
        p += (bytes + 255) & ~(size_t)255;
        return cur;
    };
    const size_t hwb_off  = take(((size_t)n_nodes + 1) * D * sizeof(unsigned short));
    const size_t cnt_off  = take((size_t)n_nodes * sizeof(int));
    const size_t off_off  = take((size_t)n_nodes * sizeof(int));
    const size_t bsum_off = take(1024 * sizeof(int));
    const size_t srcs_off = take((size_t)srcs_len * sizeof(int));
    const size_t ebuf_off = take((size_t)n_edges * sizeof(unsigned int));
    const size_t bcnt_off = take(MAXB * sizeof(int));
    const size_t boff_off = take((MAXB + 1) * sizeof(int));
    const size_t H_off    = take((size_t)EB * MAXB * sizeof(int));
    const size_t needed = p;

    char* ws = (char*)d_ws;
    unsigned short* hwb = (unsigned short*)(ws + hwb_off);

    // 1) hwb = bf16((h @ W) * norm) via MFMA
    gemm_mfma_kernel<<<(n_nodes + 63) / 64, 256, 0, stream>>>(h, W, norm, hwb, n_nodes);

    if (ws_size >= needed && NB <= 256 && NBUCK <= MAXB && n_nodes <= 131072) {
        int* cnt   = (int*)(ws + cnt_off);
        int* off   = (int*)(ws + off_off);
        int* bsums = (int*)(ws + bsum_off);
        int* srcs  = (int*)(ws + srcs_off);
        unsigned int* ebuf = (unsigned int*)(ws + ebuf_off);
        int* bcnt  = (int*)(ws + bcnt_off);
        int* boff  = (int*)(ws + boff_off);
        int* H     = (int*)(ws + H_off);

        histb_kernel<<<EB, 1024, 0, stream>>>(dst, H, hwb, n_edges, n_nodes);
        colscan_kernel<<<MAXB / 256, 256, 0, stream>>>(H, bcnt, EB);
        bscan_kernel<<<1, 256, 0, stream>>>(bcnt, boff);
        bscatter_kernel<<<EB, 1024, 0, stream>>>(src, dst, H, boff, ebuf, n_edges);
        bucket_count_kernel<<<NBUCK, 256, 0, stream>>>(ebuf, boff, cnt, n_nodes);
        scan_blocks_kernel<<<NB, 256, 0, stream>>>(cnt, off, bsums, n_nodes);
        scan_top_kernel<<<1, 256, 0, stream>>>(bsums, NB);
        scan_add_kernel<<<NB, 256, 0, stream>>>(off, bsums, n_nodes);
        fill_local_kernel<<<NBUCK, 256, 0, stream>>>(ebuf, boff, off, cnt, srcs, n_nodes);
        agg_kernel<<<(n_nodes + 7) / 8, 256, 0, stream>>>(hwb, srcs, off, cnt, norm, bias,
                                                          out, n_nodes);
    } else {
        hipMemsetAsync(d_out, 0, (size_t)out_size * sizeof(float), stream);
        const int work = n_edges * D4;
        scatter_kernel<<<(work + 255) / 256, 256, 0, stream>>>(hwb, src, dst, out, n_edges);
        const int work2 = n_nodes * D4;
        finalize_kernel<<<(work2 + 255) / 256, 256, 0, stream>>>(out, norm, bias, n_nodes);
    }
}